// Round 11
// baseline (102.688 us; speedup 1.0000x reference)
//
#include <hip/hip_runtime.h>

// A8W8 GEMM, fp16-saturating output. C = (a_i8 @ b_i8^T) * arow * acol.
// Pass 1: pack int32 -> int8. Pass 2: 256x128 tile, 4 waves, BKB=64 dbuf
// (48 KiB LDS -> TWO blocks/CU for inter-block pipe overlap, m114).
// Per K-step: P1{stage next (6 gloads), read bf23, MFMA left}, P2{MFMA
// right, vmcnt(0), BAR, read af'/bf01' from published buffer}. R3/R5's
// verified 0-conflict read + staging swizzles, byte-identical.

constexpr int MD = 4096, ND = 4096, KD = 4096;
constexpr int BM = 256, BN = 128, BKB = 64;  // K-step bytes (= MFMA K)
constexpr int NT = KD / BKB;                 // 64 K-steps

using i32x4 = __attribute__((ext_vector_type(4))) int;

#define VMCNT(n) asm volatile("s_waitcnt vmcnt(" #n ")" ::: "memory")
#define BAR() __builtin_amdgcn_s_barrier()
#define FENCE() __builtin_amdgcn_sched_barrier(0)

// ---------------- pack: int32 (one value per elem) -> int8 ----------------
__global__ __launch_bounds__(256) void pack_i8(const int* __restrict__ in,
                                               char* __restrict__ out) {
  const size_t t = (size_t)blockIdx.x * 256 + threadIdx.x;
  const int4* p = (const int4*)in + t * 4;
  int4 v0 = p[0], v1 = p[1], v2 = p[2], v3 = p[3];
  int4 o;
  o.x = v0.x | (v0.y << 8) | (v0.z << 16) | (v0.w << 24);
  o.y = v1.x | (v1.y << 8) | (v1.z << 16) | (v1.w << 24);
  o.z = v2.x | (v2.y << 8) | (v2.z << 16) | (v2.w << 24);
  o.w = v3.x | (v3.y << 8) | (v3.z << 16) | (v3.w << 24);
  ((int4*)out)[t] = o;
}

// ---------------- GEMM ----------------------------------------------------
__device__ inline void load16_lds(const char* g, char* l) {
  __builtin_amdgcn_global_load_lds(
      (const __attribute__((address_space(1))) void*)g,
      (__attribute__((address_space(3))) void*)l, 16, 0, 0);
}

// reference fp16 cast, saturating (all values >= 0; |inf-finite|=inf passes)
__device__ inline float f16_sat(float v) {
  v = fminf(v, 65504.0f);
  return (float)(_Float16)v;
}

__global__ __launch_bounds__(256, 2) void gemm_i8w8(
    const char* __restrict__ A, const char* __restrict__ B,
    const float* __restrict__ arow, const float* __restrict__ acol,
    float* __restrict__ out) {
  __shared__ char sA[2][BM * BKB];  // 2 x 16 KiB
  __shared__ char sB[2][BN * BKB];  // 2 x  8 KiB   (48 KiB total)

  const int tid = threadIdx.x;
  const int wv = tid >> 6;    // 0..3
  const int lane = tid & 63;

  // XCD-aware bijective swizzle (nwg = 512, divisible by 8)
  const int bid = blockIdx.x;
  const int wg = (bid & 7) * 64 + (bid >> 3);
  const int brow = wg >> 5;   // 16 block-rows
  const int bcol = wg & 31;   // 32 block-cols

  // 2(M) x 2(N) wave grid; per-wave output 128 x 64
  const int wrow = (wv >> 1) * 128;
  const int wcol = (wv & 1) * 64;

  i32x4 acc[8][4] = {};

  // ---- staging (R3-verified math): one gload_lds = 16 rows x 64B = 1 KiB.
  // LDS dest linear (lane l -> row +(l>>2), slot l&3); source slot
  // pre-swizzled (l&3)^((l>>3)&3), so LDS[row][s] = G[row][s^((row>>1)&3)].
  const int lr4 = lane >> 2;
  const int sg = ((lane & 3) ^ ((lane >> 3) & 3)) * 16;
  const char* aS = A + (size_t)(brow * BM + wv * 64 + lr4) * KD + sg;
  const char* bS = B + (size_t)(bcol * BN + wv * 32 + lr4) * KD + sg;

  auto STAGE = [&](int nb, size_t kb) {  // 6 gloads per wave
#pragma unroll
    for (int s = 0; s < 4; ++s)  // A rows [wv*64, wv*64+64)
      load16_lds(aS + (size_t)(s * 16) * KD + kb,
                 sA[nb] + (wv * 64 + s * 16) * BKB);
#pragma unroll
    for (int s = 0; s < 2; ++s)  // B rows [wv*32, wv*32+32)
      load16_lds(bS + (size_t)(s * 16) * KD + kb,
                 sB[nb] + (wv * 32 + s * 16) * BKB);
  };

  // ---- fragment reads (R3-verified, 0 conflicts): row = base+(lane&15);
  // G-slot = lane>>4; LDS slot = (lane>>4) ^ ((r>>1)&3).
  const int r = lane & 15;
  const int sl = ((lane >> 4) ^ ((r >> 1) & 3)) * 16;
  const int aBase = (wrow + r) * BKB + sl;  // + m*1024 per frag
  const int bBase = (wcol + r) * BKB + sl;  // + n*1024 per frag

  i32x4 af[8], bf01[2], bf23[2];

  // ---- prologue: stage buf0, drain, publish, read af + bf01
  STAGE(0, 0);
  VMCNT(0);
  BAR();
#pragma unroll
  for (int m = 0; m < 8; ++m)
    af[m] = *(const i32x4*)(sA[0] + aBase + m * 1024);
#pragma unroll
  for (int n = 0; n < 2; ++n)
    bf01[n] = *(const i32x4*)(sB[0] + bBase + n * 1024);

  // ---- one 64B K-step: 2 MFMA clusters, 1 barrier, 1 vmcnt.
  auto step = [&](int i, int cb, int nb) {
    const bool more = (i + 1) < NT;
    const size_t kb = (size_t)(i + 1) * BKB;
    // P1: stage next buffer; read bf23(cur); MFMA left (m0-7 x n0-1)
    if (more) STAGE(nb, kb);
#pragma unroll
    for (int n = 0; n < 2; ++n)
      bf23[n] = *(const i32x4*)(sB[cb] + bBase + (n + 2) * 1024);
    __builtin_amdgcn_s_setprio(1);
#pragma unroll
    for (int m = 0; m < 8; ++m)
#pragma unroll
      for (int n = 0; n < 2; ++n)
        acc[m][n] = __builtin_amdgcn_mfma_i32_16x16x64_i8(af[m], bf01[n],
                                                          acc[m][n], 0, 0, 0);
    __builtin_amdgcn_s_setprio(0);
    FENCE();
    // P2: MFMA right (m0-7 x n2-3); drain stage; publish; read next frags
    __builtin_amdgcn_s_setprio(1);
#pragma unroll
    for (int m = 0; m < 8; ++m)
#pragma unroll
      for (int n = 0; n < 2; ++n)
        acc[m][n + 2] = __builtin_amdgcn_mfma_i32_16x16x64_i8(
            af[m], bf23[n], acc[m][n + 2], 0, 0, 0);
    __builtin_amdgcn_s_setprio(0);
    VMCNT(0);  // stage(nb) landed; other co-resident block hides this drain
    BAR();
    if (more) {
#pragma unroll
      for (int m = 0; m < 8; ++m)
        af[m] = *(const i32x4*)(sA[nb] + aBase + m * 1024);
#pragma unroll
      for (int n = 0; n < 2; ++n)
        bf01[n] = *(const i32x4*)(sB[nb] + bBase + n * 1024);
    }
    FENCE();
  };

  for (int i = 0; i < NT; i += 2) {  // static buffer parity
    step(i, 0, 1);
    step(i + 1, 1, 0);
  }

  // ---- epilogue: C/D map col=lane&15, row=(lane>>4)*4+reg (16x16 shapes)
  const int orow0 = brow * BM + wrow + ((lane >> 4) << 2);
  const int ocol0 = bcol * BN + wcol + (lane & 15);
#pragma unroll
  for (int m = 0; m < 8; ++m) {
    const int rb = orow0 + m * 16;
    const float ar0 = arow[rb + 0], ar1 = arow[rb + 1];
    const float ar2 = arow[rb + 2], ar3 = arow[rb + 3];
#pragma unroll
    for (int n = 0; n < 4; ++n) {
      const int col = ocol0 + n * 16;
      const float ac = acol[col];
      out[(size_t)(rb + 0) * ND + col] = f16_sat((float)acc[m][n][0] * (ar0 * ac));
      out[(size_t)(rb + 1) * ND + col] = f16_sat((float)acc[m][n][1] * (ar1 * ac));
      out[(size_t)(rb + 2) * ND + col] = f16_sat((float)acc[m][n][2] * (ar2 * ac));
      out[(size_t)(rb + 3) * ND + col] = f16_sat((float)acc[m][n][3] * (ar3 * ac));
    }
  }
}

extern "C" void kernel_launch(void* const* d_in, const int* in_sizes, int n_in,
                              void* d_out, int out_size, void* d_ws, size_t ws_size,
                              hipStream_t stream) {
  const int* a = (const int*)d_in[0];         // [M,K] int32 (int8 values)
  const int* b = (const int*)d_in[1];         // [N,K] int32 (int8 values)
  const float* arow = (const float*)d_in[2];  // [M,1]
  const float* acol = (const float*)d_in[3];  // [1,N]
  float* out = (float*)d_out;

  char* pa = (char*)d_ws;                    // 16 MiB packed A
  char* pb = pa + (size_t)MD * KD;           // 16 MiB packed B

  const int packBlocks = (int)(((size_t)MD * KD) / (16 * 256));  // 4096
  pack_i8<<<packBlocks, 256, 0, stream>>>(a, pa);
  pack_i8<<<packBlocks, 256, 0, stream>>>(b, pb);

  const int grid = (MD / BM) * (ND / BN);  // 512 blocks, 2 per CU
  gemm_i8w8<<<grid, 256, 0, stream>>>(pa, pb, arow, acol, out);
}